// Round 2
// baseline (89.303 us; speedup 1.0000x reference)
//
#include <hip/hip_runtime.h>
#include <math.h>

#define FF 512
#define SIGMAINV 7000.0f
#define EPSF 1e-10f
#define NW 8           // waves per block (kernel 2)
#define FPW (FF / NW)  // faces per wave chunk = 64
#define RSTRIDE 32     // floats per face record in ws

// ws record layout (32 floats = 128 B, s_load friendly):
//  [0..3]  bbox: bx0 bx1 by0 by1   (empty box if !(front&valid))
//  [4..9]  x0 y0 x1 y1 x2 y2       (screen verts)
//  [10..12] z0 z1 z2               (cam-space z)
//  [13]    1/denom
//  [14..16] e0: abx aby 1/(|ab|^2+eps)
//  [17..19] e1
//  [20..22] e2
//  [23..31] colors: c0.rgb c1.rgb c2.rgb
//
// out layout: imrender [0,49152) ; improb [49152,65536) ; normal1 [65536,67072)

__global__ __launch_bounds__(512, 1) void vc_setup_kernel(
    const float* __restrict__ points,   // 256*3
    const float* __restrict__ colors,   // 256*3
    const float* __restrict__ rot,      // 3*3
    const float* __restrict__ cpos,     // 3
    const float* __restrict__ proj,     // 3
    const int*   __restrict__ faces,    // 512*3
    float* __restrict__ out,
    float* __restrict__ ws)
{
#pragma clang fp contract(off)
    const int f = threadIdx.x;  // 512 threads == 512 faces
    const int i0 = faces[f * 3 + 0];
    const int i1 = faces[f * 3 + 1];
    const int i2 = faces[f * 3 + 2];
    const float r00 = rot[0], r01 = rot[1], r02 = rot[2];
    const float r10 = rot[3], r11 = rot[4], r12 = rot[5];
    const float r20 = rot[6], r21 = rot[7], r22 = rot[8];
    const float cx = cpos[0], cy = cpos[1], cz = cpos[2];
    const float pjx = proj[0], pjy = proj[1], pjz = proj[2];

    float camx[3], camy[3], camz[3], sx[3], sy[3];
    const int vidx[3] = {i0, i1, i2};
    for (int k = 0; k < 3; ++k) {
        const int vi = vidx[k];
        const float ax = points[vi * 3 + 0] - cx;
        const float ay = points[vi * 3 + 1] - cy;
        const float az = points[vi * 3 + 2] - cz;
        const float X = r00 * ax + r01 * ay + r02 * az;
        const float Y = r10 * ax + r11 * ay + r12 * az;
        const float Z = r20 * ax + r21 * ay + r22 * az;
        camx[k] = X; camy[k] = Y; camz[k] = Z;
        const float zz = Z * pjz;
        sx[k] = (X * pjx) / zz;
        sy[k] = (Y * pjy) / zz;
    }
    // face normal in cam space
    const float e1x = camx[1] - camx[0], e1y = camy[1] - camy[0], e1z = camz[1] - camz[0];
    const float e2x = camx[2] - camx[0], e2y = camy[2] - camy[0], e2z = camz[2] - camz[0];
    const float nx = e1y * e2z - e1z * e2y;
    const float ny = e1z * e2x - e1x * e2z;
    const float nz = e1x * e2y - e1y * e2x;
    const float nlen = sqrtf(nx * nx + ny * ny + nz * nz + 1e-8f);
    const float ninv = 1.0f / (nlen + 1e-15f);
    out[65536 + f * 3 + 0] = nx * ninv;
    out[65536 + f * 3 + 1] = ny * ninv;
    out[65536 + f * 3 + 2] = nz * ninv;

    const float x0 = sx[0], y0 = sy[0], x1 = sx[1], y1 = sy[1], x2 = sx[2], y2 = sy[2];
    const float area = (x1 - x0) * (y2 - y0) - (x2 - x0) * (y1 - y0);
    const bool valid = fabsf(area) > EPSF;
    const float denom = valid ? area : EPSF;
    const float invd = 1.0f / denom;
    const bool fv = (nz > 0.0f) && valid;

    float* r = &ws[f * RSTRIDE];
    // inflated bbox: outside it, exp(-d2*SIGMAINV) < 6e-14 -> face contributes nothing
    const float RM = 0.0660f;  // > sqrt(30/7000)
    if (fv) {
        r[0] = fminf(fminf(x0, x1), x2) - RM;
        r[1] = fmaxf(fmaxf(x0, x1), x2) + RM;
        r[2] = fminf(fminf(y0, y1), y2) - RM;
        r[3] = fmaxf(fmaxf(y0, y1), y2) + RM;
    } else {
        r[0] = 1e30f; r[1] = -1e30f; r[2] = 1e30f; r[3] = -1e30f;  // empty
    }
    r[4] = x0; r[5] = y0; r[6] = x1; r[7] = y1; r[8] = x2; r[9] = y2;
    r[10] = camz[0]; r[11] = camz[1]; r[12] = camz[2];
    r[13] = invd;
    const float ab0x = x1 - x0, ab0y = y1 - y0;
    const float ab1x = x2 - x1, ab1y = y2 - y1;
    const float ab2x = x0 - x2, ab2y = y0 - y2;
    r[14] = ab0x; r[15] = ab0y; r[16] = 1.0f / (ab0x * ab0x + ab0y * ab0y + EPSF);
    r[17] = ab1x; r[18] = ab1y; r[19] = 1.0f / (ab1x * ab1x + ab1y * ab1y + EPSF);
    r[20] = ab2x; r[21] = ab2y; r[22] = 1.0f / (ab2x * ab2x + ab2y * ab2y + EPSF);
    r[23] = colors[i0 * 3 + 0]; r[24] = colors[i0 * 3 + 1]; r[25] = colors[i0 * 3 + 2];
    r[26] = colors[i1 * 3 + 0]; r[27] = colors[i1 * 3 + 1]; r[28] = colors[i1 * 3 + 2];
    r[29] = colors[i2 * 3 + 0]; r[30] = colors[i2 * 3 + 1]; r[31] = colors[i2 * 3 + 2];
}

__global__ __launch_bounds__(512, 1) void vc_raster_kernel(
    const float* __restrict__ ws,   // face records, read-only here
    float* __restrict__ out)
{
#pragma clang fp contract(off)
    __shared__ float redz[NW * 64];
    __shared__ int   redi[NW * 64];
    __shared__ float redp[NW * 64];

    const int tid  = threadIdx.x;
    // force wave-uniformity so face-record loads select the scalar (SMEM) path
    const int wv   = __builtin_amdgcn_readfirstlane(tid >> 6);  // 0..7 face chunk
    const int lane = tid & 63;                                  // 0..63 pixel
    const int pix  = blockIdx.x * 64 + lane;                    // 0..16383
    const float px = ((pix & 127) + 0.5f) * (2.0f / 128.0f) - 1.0f;
    const float py = 1.0f - ((pix >> 7) + 0.5f) * (2.0f / 128.0f);

    float zmin = INFINITY;
    int   fmin = 0;
    float prod = 1.0f;

    const int fbeg = wv * FPW;
    for (int f = fbeg; f < fbeg + FPW; ++f) {
        const float* r = &ws[f * RSTRIDE];
        const float bx0 = r[0], bx1 = r[1], by0 = r[2], by1 = r[3];
        if (px >= bx0 && px <= bx1 && py >= by0 && py <= by1) {
            const float x0 = r[4], y0 = r[5], x1 = r[6], y1 = r[7], x2 = r[8], y2 = r[9];
            const float invd = r[13];
            const float w0 = ((x1 - px) * (y2 - py) - (x2 - px) * (y1 - py)) * invd;
            const float w1 = ((x2 - px) * (y0 - py) - (x0 - px) * (y2 - py)) * invd;
            const float w2 = 1.0f - w0 - w1;
            const bool inside = (w0 >= 0.0f) && (w1 >= 0.0f) && (w2 >= 0.0f);
            const float z = w0 * r[10] + w1 * r[11] + w2 * r[12];
            if (inside && z < zmin) { zmin = z; fmin = f; }
            // min squared distance to the 3 edges
            float apx, apy, t, dx, dy;
            apx = px - x0; apy = py - y0;
            t = fminf(fmaxf((apx * r[14] + apy * r[15]) * r[16], 0.0f), 1.0f);
            dx = apx - t * r[14]; dy = apy - t * r[15];
            float d2 = dx * dx + dy * dy;
            apx = px - x1; apy = py - y1;
            t = fminf(fmaxf((apx * r[17] + apy * r[18]) * r[19], 0.0f), 1.0f);
            dx = apx - t * r[17]; dy = apy - t * r[18];
            d2 = fminf(d2, dx * dx + dy * dy);
            apx = px - x2; apy = py - y2;
            t = fminf(fmaxf((apx * r[20] + apy * r[21]) * r[22], 0.0f), 1.0f);
            dx = apx - t * r[20]; dy = apy - t * r[21];
            d2 = fminf(d2, dx * dx + dy * dy);
            d2 = inside ? 0.0f : d2;
            prod *= (1.0f - __expf(-d2 * SIGMAINV));
        }
    }

    redz[wv * 64 + lane] = zmin;
    redi[wv * 64 + lane] = fmin;
    redp[wv * 64 + lane] = prod;
    __syncthreads();

    // ---------------- combine chunks + epilogue (wave 0) ----------------
    if (wv == 0) {
        float z = zmin; int fi = fmin; float pr = prod;
        for (int c = 1; c < NW; ++c) {
            const float zc = redz[c * 64 + lane];
            const float pc = redp[c * 64 + lane];
            const int   ic = redi[c * 64 + lane];
            if (zc < z) { z = zc; fi = ic; }   // ascending chunks: first-min tiebreak
            pr *= pc;
        }
        float fr = 0.0f, fg = 0.0f, fb = 0.0f;
        if (z < INFINITY) {  // hit: lane-varying face -> vector loads (cold path, cheap)
            const float* r = &ws[fi * RSTRIDE];
            const float x0 = r[4], y0 = r[5], x1 = r[6], y1 = r[7], x2 = r[8], y2 = r[9];
            const float invd = r[13];
            const float w0 = ((x1 - px) * (y2 - py) - (x2 - px) * (y1 - py)) * invd;
            const float w1 = ((x2 - px) * (y0 - py) - (x0 - px) * (y2 - py)) * invd;
            const float w2 = 1.0f - w0 - w1;
            fr = w0 * r[23] + w1 * r[26] + w2 * r[29];
            fg = w0 * r[24] + w1 * r[27] + w2 * r[30];
            fb = w0 * r[25] + w1 * r[28] + w2 * r[31];
        }
        out[pix * 3 + 0] = fr;
        out[pix * 3 + 1] = fg;
        out[pix * 3 + 2] = fb;
        out[3 * 16384 + pix] = 1.0f - pr;
    }
}

extern "C" void kernel_launch(void* const* d_in, const int* in_sizes, int n_in,
                              void* d_out, int out_size, void* d_ws, size_t ws_size,
                              hipStream_t stream) {
    const float* points = (const float*)d_in[0];
    const float* colors = (const float*)d_in[1];
    const float* rot    = (const float*)d_in[2];
    const float* cpos   = (const float*)d_in[3];
    const float* proj   = (const float*)d_in[4];
    const int*   faces  = (const int*)d_in[5];
    float* out = (float*)d_out;
    float* ws  = (float*)d_ws;
    vc_setup_kernel<<<1, 512, 0, stream>>>(points, colors, rot, cpos, proj, faces, out, ws);
    vc_raster_kernel<<<256, 512, 0, stream>>>(ws, out);
}

// Round 3
// 74.845 us; speedup vs baseline: 1.1932x; 1.1932x over previous
//
#include <hip/hip_runtime.h>
#include <math.h>

#define FF 512
#define SIGMAINV 7000.0f
#define EPSF 1e-10f
#define NW 8           // waves per block
#define RMF 0.0660f    // bbox inflation: exp(-RM^2*7000) < 6e-14, below fp32 noise

// out layout: imrender [0,49152) ; improb [49152,65536) ; normal1 [65536,67072)
//
// Block b covers pixels [64b, 64b+64) = one 64-wide strip of a single image row
// (py is block-uniform). Setup compacts the faces whose inflated bbox overlaps
// the strip into LDS (order-preserving -> argmin tie-break matches reference).
// Record = 4 x float4 per face -> ds_read_b128 broadcast reads in the hot loop.

__global__ __launch_bounds__(512, 1) void vcrender_kernel(
    const float* __restrict__ points,   // 256*3
    const float* __restrict__ colors,   // 256*3
    const float* __restrict__ rot,      // 3*3
    const float* __restrict__ cpos,     // 3
    const float* __restrict__ proj,     // 3
    const int*   __restrict__ faces,    // 512*3
    float* __restrict__ out)
{
#pragma clang fp contract(off)
    __shared__ float4 srec[FF * 4];    // compacted face records (32 KB max)
    __shared__ int    scount[NW];
    __shared__ int    sbase[NW];
    __shared__ int    stotal;
    __shared__ float  redz[NW * 64];
    __shared__ int    redi[NW * 64];
    __shared__ float  redp[NW * 64];

    const int tid  = threadIdx.x;
    const int lane = tid & 63;
    const int wv   = tid >> 6;

    // this block's pixel strip (single row)
    const int   pixbase = blockIdx.x * 64;
    const float py    = 1.0f - ((pixbase >> 7) + 0.5f) * (2.0f / 128.0f);    // uniform
    const float pxmin = ((pixbase & 127) + 0.5f) * (2.0f / 128.0f) - 1.0f;
    const float pxmax = ((pixbase & 127) + 63 + 0.5f) * (2.0f / 128.0f) - 1.0f;

    // ---------------- per-face setup + strip culling (one face per thread) ----
    bool  flag = false;
    float4 q0, q1, q2, q3;
    {
        const int f  = tid;  // 512 threads == 512 faces
        const int i0 = faces[f * 3 + 0];
        const int i1 = faces[f * 3 + 1];
        const int i2 = faces[f * 3 + 2];
        const float r00 = rot[0], r01 = rot[1], r02 = rot[2];
        const float r10 = rot[3], r11 = rot[4], r12 = rot[5];
        const float r20 = rot[6], r21 = rot[7], r22 = rot[8];
        const float cx = cpos[0], cy = cpos[1], cz = cpos[2];
        const float pjx = proj[0], pjy = proj[1], pjz = proj[2];

        float camx[3], camy[3], camz[3], sx[3], sy[3];
        const int vidx[3] = {i0, i1, i2};
        for (int k = 0; k < 3; ++k) {
            const int vi = vidx[k];
            const float ax = points[vi * 3 + 0] - cx;
            const float ay = points[vi * 3 + 1] - cy;
            const float az = points[vi * 3 + 2] - cz;
            const float X = r00 * ax + r01 * ay + r02 * az;
            const float Y = r10 * ax + r11 * ay + r12 * az;
            const float Z = r20 * ax + r21 * ay + r22 * az;
            camx[k] = X; camy[k] = Y; camz[k] = Z;
            const float zz = Z * pjz;
            sx[k] = (X * pjx) / zz;
            sy[k] = (Y * pjy) / zz;
        }
        const float e1x = camx[1] - camx[0], e1y = camy[1] - camy[0], e1z = camz[1] - camz[0];
        const float e2x = camx[2] - camx[0], e2y = camy[2] - camy[0], e2z = camz[2] - camz[0];
        const float nx = e1y * e2z - e1z * e2y;
        const float ny = e1z * e2x - e1x * e2z;
        const float nz = e1x * e2y - e1y * e2x;
        const float nlen = sqrtf(nx * nx + ny * ny + nz * nz + 1e-8f);
        const float ninv = 1.0f / (nlen + 1e-15f);
        if (blockIdx.x == 0) {
            out[65536 + f * 3 + 0] = nx * ninv;
            out[65536 + f * 3 + 1] = ny * ninv;
            out[65536 + f * 3 + 2] = nz * ninv;
        }
        const float x0 = sx[0], y0 = sy[0], x1 = sx[1], y1 = sy[1], x2 = sx[2], y2 = sy[2];
        const float area = (x1 - x0) * (y2 - y0) - (x2 - x0) * (y1 - y0);
        const bool valid = fabsf(area) > EPSF;
        const float denom = valid ? area : EPSF;
        const float invd = 1.0f / denom;
        const bool fv = (nz > 0.0f) && valid;

        const float bx0 = fminf(fminf(x0, x1), x2) - RMF;
        const float bx1 = fmaxf(fmaxf(x0, x1), x2) + RMF;
        const float by0 = fminf(fminf(y0, y1), y2) - RMF;
        const float by1 = fmaxf(fmaxf(y0, y1), y2) + RMF;
        flag = fv && (by0 <= py) && (by1 >= py) && (bx0 <= pxmax) && (bx1 >= pxmin);

        const float ab0x = x1 - x0, ab0y = y1 - y0;
        const float ab1x = x2 - x1, ab1y = y2 - y1;
        const float ab2x = x0 - x2, ab2y = y0 - y2;
        q0 = make_float4(bx0, bx1, invd, camz[0]);
        q1 = make_float4(x0, y0, x1, y1);
        q2 = make_float4(x2, y2, camz[1], camz[2]);
        q3 = make_float4(1.0f / (ab0x * ab0x + ab0y * ab0y + EPSF),
                         1.0f / (ab1x * ab1x + ab1y * ab1y + EPSF),
                         1.0f / (ab2x * ab2x + ab2y * ab2y + EPSF),
                         __int_as_float(f));
    }
    const unsigned long long mask = __ballot(flag);
    if (lane == 0) scount[wv] = __popcll(mask);
    __syncthreads();
    if (tid == 0) {
        int s = 0;
        for (int i = 0; i < NW; ++i) { sbase[i] = s; s += scount[i]; }
        stotal = s;
    }
    __syncthreads();
    if (flag) {
        const int pos = sbase[wv] + __popcll(mask & ((1ull << lane) - 1ull));
        srec[pos * 4 + 0] = q0;
        srec[pos * 4 + 1] = q1;
        srec[pos * 4 + 2] = q2;
        srec[pos * 4 + 3] = q3;
    }
    __syncthreads();
    const int n = stotal;

    // ---------------- raster: wave = contiguous slot chunk, lane = pixel ------
    const int pix = pixbase + lane;
    const float px = ((pix & 127) + 0.5f) * (2.0f / 128.0f) - 1.0f;

    float zmin = INFINITY;
    int   smin = 0;
    float prod = 1.0f;

    const int chunk = (n + NW - 1) >> 3;
    const int fbeg = wv * chunk;
    const int fend = min(fbeg + chunk, n);
    for (int s = fbeg; s < fend; ++s) {
        const float4 b = srec[s * 4 + 0];
        if (px >= b.x && px <= b.y) {
            const float4 v01 = srec[s * 4 + 1];
            const float4 v2z = srec[s * 4 + 2];
            const float x0 = v01.x, y0 = v01.y, x1 = v01.z, y1 = v01.w;
            const float x2 = v2z.x, y2 = v2z.y;
            const float invd = b.z;
            const float w0 = ((x1 - px) * (y2 - py) - (x2 - px) * (y1 - py)) * invd;
            const float w1 = ((x2 - px) * (y0 - py) - (x0 - px) * (y2 - py)) * invd;
            const float w2 = 1.0f - w0 - w1;
            const float z = w0 * b.w + w1 * v2z.z + w2 * v2z.w;
            if (w0 >= 0.0f && w1 >= 0.0f && w2 >= 0.0f) {
                if (z < zmin) { zmin = z; smin = s; }   // ascending slots: first-min tiebreak
                prod = 0.0f;                            // d2=0 -> factor (1-e^0)=0
            } else {
                const float4 ei = srec[s * 4 + 3];
                const float ab0x = x1 - x0, ab0y = y1 - y0;
                const float ab1x = x2 - x1, ab1y = y2 - y1;
                const float ab2x = x0 - x2, ab2y = y0 - y2;
                float apx, apy, t, dx, dy;
                apx = px - x0; apy = py - y0;
                t = fminf(fmaxf((apx * ab0x + apy * ab0y) * ei.x, 0.0f), 1.0f);
                dx = apx - t * ab0x; dy = apy - t * ab0y;
                float d2 = dx * dx + dy * dy;
                apx = px - x1; apy = py - y1;
                t = fminf(fmaxf((apx * ab1x + apy * ab1y) * ei.y, 0.0f), 1.0f);
                dx = apx - t * ab1x; dy = apy - t * ab1y;
                d2 = fminf(d2, dx * dx + dy * dy);
                apx = px - x2; apy = py - y2;
                t = fminf(fmaxf((apx * ab2x + apy * ab2y) * ei.z, 0.0f), 1.0f);
                dx = apx - t * ab2x; dy = apy - t * ab2y;
                d2 = fminf(d2, dx * dx + dy * dy);
                prod *= (1.0f - __expf(-d2 * SIGMAINV));
            }
        }
    }

    redz[wv * 64 + lane] = zmin;
    redi[wv * 64 + lane] = smin;
    redp[wv * 64 + lane] = prod;
    __syncthreads();

    // ---------------- combine chunks + epilogue (wave 0) ----------------
    if (wv == 0) {
        float z = zmin; int si = smin; float pr = prod;
        for (int c = 1; c < NW; ++c) {
            const float zc = redz[c * 64 + lane];
            const float pc = redp[c * 64 + lane];
            const int   ic = redi[c * 64 + lane];
            if (zc < z) { z = zc; si = ic; }   // chunks ascending: first-min tiebreak
            pr *= pc;
        }
        float fr = 0.0f, fg = 0.0f, fb = 0.0f;
        if (z < INFINITY) {  // hit: cold path, lane-varying gathers are fine
            const float4 b   = srec[si * 4 + 0];
            const float4 v01 = srec[si * 4 + 1];
            const float4 v2z = srec[si * 4 + 2];
            const float x0 = v01.x, y0 = v01.y, x1 = v01.z, y1 = v01.w;
            const float x2 = v2z.x, y2 = v2z.y;
            const float invd = b.z;
            const float w0 = ((x1 - px) * (y2 - py) - (x2 - px) * (y1 - py)) * invd;
            const float w1 = ((x2 - px) * (y0 - py) - (x0 - px) * (y2 - py)) * invd;
            const float w2 = 1.0f - w0 - w1;
            const int fid = __float_as_int(srec[si * 4 + 3].w);
            const int i0 = faces[fid * 3 + 0], i1 = faces[fid * 3 + 1], i2 = faces[fid * 3 + 2];
            fr = w0 * colors[i0 * 3 + 0] + w1 * colors[i1 * 3 + 0] + w2 * colors[i2 * 3 + 0];
            fg = w0 * colors[i0 * 3 + 1] + w1 * colors[i1 * 3 + 1] + w2 * colors[i2 * 3 + 1];
            fb = w0 * colors[i0 * 3 + 2] + w1 * colors[i1 * 3 + 2] + w2 * colors[i2 * 3 + 2];
        }
        out[pix * 3 + 0] = fr;
        out[pix * 3 + 1] = fg;
        out[pix * 3 + 2] = fb;
        out[3 * 16384 + pix] = 1.0f - pr;
    }
}

extern "C" void kernel_launch(void* const* d_in, const int* in_sizes, int n_in,
                              void* d_out, int out_size, void* d_ws, size_t ws_size,
                              hipStream_t stream) {
    const float* points = (const float*)d_in[0];
    const float* colors = (const float*)d_in[1];
    const float* rot    = (const float*)d_in[2];
    const float* cpos   = (const float*)d_in[3];
    const float* proj   = (const float*)d_in[4];
    const int*   faces  = (const int*)d_in[5];
    float* out = (float*)d_out;
    vcrender_kernel<<<256, 512, 0, stream>>>(points, colors, rot, cpos, proj, faces, out);
}